// Round 1
// baseline (357.618 us; speedup 1.0000x reference)
//
#include <hip/hip_runtime.h>

// GymNetwork: routed MLP, B=262144, D=128 -> F=80 -> 80 -> 80 -> A=18, G=8 (idx sorted).
// f32 I/O, bf16 MFMA compute (threshold 6e-2 = 8*bf16_eps*max|ref|).
//
// R11 (from R10 @ ~219us total, gym_fused <= ~76us per trace):
// (1) 32 rows/wave: two 16-row B-fragment tiles share every W1 ds_read_b128 -> LDS
//     W-read traffic per row halves. SLAB=256 (8 waves x 32), NSLAB=2, GRID=512 (2/CU).
// (2) W2/W3/W4 fragments from GLOBAL (66KB, L1/L2-resident, 1KB/wave coalesced) -> LDS
//     pipe only carries W1 + h round-trip (~9us/CU), overlaps HBM instead of summing.
// (3) b1 folded into W1 as k=128 column (ks=4 chunk) x constant-1.0 B-frag: frees the
//     20-VGPR b1v array to pay for the doubled accumulator set (peak ~110 VGPR < 128).

#define B_TOT   262144
#define DDIM    128
#define FDIM    80
#define ADIM    18
#define SH      104    // LDS stride (shorts) for h rows; 208B = 13*16 keeps b128 aligned
#define THREADS 512
#define SLAB    256    // rows per block-iteration (8 waves x 32)
#define NSLAB   2      // block rows = 512
#define GRID    (B_TOT / (SLAB * NSLAB))   // 512 blocks = 2/CU

// swizzled bf16 weight workspace in d_ws (shorts); 512-short (1KB) chunks, lane-major
#define W1SW    0                       // 200 chunks: (g*25 + ks*5 + ct); ks=4 = b1 col
#define W2SW    102400                  // 15 chunks: (ks*5+ct); k=80 holds b2, 81..95 zero
#define W3SW    110080                  // 15 chunks; k=80 holds b3
#define W4SW    117760                  // 48 chunks: (g*6+ks*2+ct); k=80 holds b4
#define NCHUNK  278
#define WTOT    (NCHUNK * 512)          // 142336 shorts = 284672 bytes

// LDS layout (shorts)
#define LW1     0                       // 25 chunks (current g) = 12800
#define LHB     12800                   // 8 waves x 32 x SH = 26624
#define LDS_SH  39424                   // 78848 B -> 2 blocks/CU

typedef __attribute__((ext_vector_type(8))) short short8;
typedef __attribute__((ext_vector_type(2))) unsigned int uint2v;
typedef __attribute__((ext_vector_type(4))) float floatx4;
typedef __attribute__((ext_vector_type(2))) float floatx2;

static __device__ __forceinline__ unsigned short f2bf(float f) {
  union { float f; unsigned u; } v; v.f = f;
  unsigned r = v.u + 0x7fffu + ((v.u >> 16) & 1u);   // RNE
  return (unsigned short)(r >> 16);
}
// pack two f32 -> bf16x2 (lo | hi<<16), RNE
static __device__ __forceinline__ unsigned pk2(float a, float b) {
  union { float f; unsigned u; } x, y; x.f = a; y.f = b;
  unsigned ra = x.u + 0x7fffu + ((x.u >> 16) & 1u);
  unsigned rb = y.u + 0x7fffu + ((y.u >> 16) & 1u);
  return (ra >> 16) | (rb & 0xffff0000u);
}

// ---- prologue: f32 weights -> bf16 swizzled chunks; biases folded into extra-k cols ----
// chunk: ws[chunk*512 + lane*8 + j] = W[n = ct*16 + (lane&15)][k = ks*32 + (lane>>4)*8 + j]
__global__ void convert_weights(const float* __restrict__ W1, const float* __restrict__ b1,
                                const float* __restrict__ W2, const float* __restrict__ W3,
                                const float* __restrict__ W4, const float* __restrict__ b2,
                                const float* __restrict__ b3, const float* __restrict__ b4,
                                unsigned short* __restrict__ ws) {
  int t = blockIdx.x * 256 + threadIdx.x;
  if (t >= WTOT) return;
  int chunk = t >> 9, r = t & 511;
  int lane = r >> 3, j = r & 7;
  int l16 = lane & 15, quad = lane >> 4;
  float val;
  if (chunk < 200) {                              // W1: [G][80][128] + ks=4 bias col
    int g = chunk / 25, rem = chunk % 25, ks = rem / 5, ct = rem % 5;
    int n = ct * 16 + l16, k = ks * 32 + quad * 8 + j;
    val = (ks < 4) ? W1[(g * FDIM + n) * DDIM + k]
                   : ((quad == 0 && j == 0) ? b1[g * FDIM + n] : 0.f);
  } else if (chunk < 215) {                       // W2: 80x80 -> 80x96, k80 = b2[n]
    int c = chunk - 200, ks = c / 5, ct = c % 5;
    int n = ct * 16 + l16, k = ks * 32 + quad * 8 + j;
    val = (k < FDIM) ? W2[n * FDIM + k] : (k == FDIM ? b2[n] : 0.f);
  } else if (chunk < 230) {                       // W3, k80 = b3[n]
    int c = chunk - 215, ks = c / 5, ct = c % 5;
    int n = ct * 16 + l16, k = ks * 32 + quad * 8 + j;
    val = (k < FDIM) ? W3[n * FDIM + k] : (k == FDIM ? b3[n] : 0.f);
  } else {                                        // W4: Gx18x80 -> Gx32x96, k80 = b4[g][n]
    int c = chunk - 230, g = c / 6, rem = c % 6, ks = rem >> 1, ct = rem & 1;
    int n = ct * 16 + l16, k = ks * 32 + quad * 8 + j;
    val = (n < ADIM) ? ((k < FDIM) ? W4[(g * ADIM + n) * FDIM + k]
                                   : (k == FDIM ? b4[g * ADIM + n] : 0.f)) : 0.f;
  }
  ws[t] = f2bf(val);
}

// W1[g] (25 chunks incl. bias col) -> LDS; barrier pair; block-uniform call sites
static __device__ __forceinline__ void stage_game(
    int g, const unsigned short* __restrict__ wsw, unsigned short* smem, int tid)
{
  __syncthreads();                                // all waves done with old W1
  const short8* src = (const short8*)(wsw + W1SW + g * (25 * 512));
  short8* dst = (short8*)(smem + LW1);
#pragma unroll
  for (int i = 0; i < 4; ++i) {
    int t = i * THREADS + tid;
    if (t < 1600) dst[t] = src[t];
  }
  __syncthreads();                                // new W1 visible
}

__global__ __launch_bounds__(THREADS, 4) void gym_fused(
    const float* __restrict__ state, const int* __restrict__ idx,
    const unsigned short* __restrict__ wsw, float* __restrict__ out)
{
  __shared__ __align__(16) unsigned short smem[LDS_SH];

  const int tid  = threadIdx.x;
  const int lane = tid & 63;
  const int wv   = tid >> 6;
  const int l16  = lane & 15;
  const int quad = lane >> 4;
  unsigned short* hbuf = smem + LHB + wv * (32 * SH);
  const size_t blk0 = (size_t)blockIdx.x * (SLAB * NSLAB);

  // ---- hbuf pad cols 80..95 for all 32 rows: col80 = 1.0 (bias-in-k), 81..95 = 0 ----
  {
    int row = lane >> 1, grp = lane & 1;          // 32 rows x 2 groups of 8 shorts
    short8 v = (short8){0, 0, 0, 0, 0, 0, 0, 0};
    if (grp == 0) v[0] = (short)0x3F80;           // bf16 1.0 at col 80
    *(short8*)(hbuf + row * SH + 80 + grp * 8) = v;
  }

  // ---- constant B-frag for L1's ks=4 bias chunk: 1.0 at k=128 (quad 0, j 0) ----
  short8 bfrag = (short8){0, 0, 0, 0, 0, 0, 0, 0};
  if (quad == 0) bfrag[0] = (short)0x3F80;

  // ---- initial game (covered by stage_game's barrier pair) ----
  int curr_g = idx[blk0];
  stage_game(curr_g, wsw, smem, tid);

  for (int it = 0; it < NSLAB; ++it) {
    const size_t slab0 = blk0 + (size_t)it * SLAB;
    const size_t trow  = slab0 + wv * 32;         // this wave's 32 rows (2 x 16 tiles)
    const int tg_lo = idx[slab0];
    const int tg_hi = idx[slab0 + SLAB - 1];      // idx sorted
    const int midxA = idx[trow + l16];            // tile-A lane row's game
    const int midxB = idx[trow + 16 + l16];       // tile-B lane row's game

    // ---- state B'-fragments for both tiles: row = l16, k = quad*8+j ----
    short8 afrag[2][4];
#pragma unroll
    for (int t = 0; t < 2; ++t) {
      const float* sp = state + (trow + t * 16 + l16) * DDIM + quad * 8;
#pragma unroll
      for (int ks = 0; ks < 4; ++ks) {
        floatx4 va = *(const floatx4*)(sp + ks * 32);
        floatx4 vb = *(const floatx4*)(sp + ks * 32 + 4);
        short8 f;
        unsigned u0 = pk2(va[0], va[1]), u1 = pk2(va[2], va[3]);
        unsigned u2 = pk2(vb[0], vb[1]), u3 = pk2(vb[2], vb[3]);
        f[0] = (short)(u0 & 0xffff); f[1] = (short)(u0 >> 16);
        f[2] = (short)(u1 & 0xffff); f[3] = (short)(u1 >> 16);
        f[4] = (short)(u2 & 0xffff); f[5] = (short)(u2 >> 16);
        f[6] = (short)(u3 & 0xffff); f[7] = (short)(u3 >> 16);
        afrag[t][ks] = f;
      }
    }

    for (int g = tg_lo; g <= tg_hi; ++g) {        // block-uniform loop (slab range)
      if (g != curr_g) { stage_game(g, wsw, smem, tid); curr_g = g; }

      // ---- L1 interleaved over both tiles: each W1 ds_read feeds 2 MFMAs.
      //      ks=4 carries b1 (A col k=128) x bfrag (1.0). ----
      {
        floatx4 accA[5], accB[5];
#pragma unroll
        for (int ct = 0; ct < 5; ++ct) {
          accA[ct] = (floatx4){0.f, 0.f, 0.f, 0.f};
          accB[ct] = (floatx4){0.f, 0.f, 0.f, 0.f};
        }
#pragma unroll
        for (int ks = 0; ks < 5; ++ks) {
          short8 bA = (ks < 4) ? afrag[0][ks] : bfrag;
          short8 bB = (ks < 4) ? afrag[1][ks] : bfrag;
#pragma unroll
          for (int ct = 0; ct < 5; ++ct) {
            short8 wf = *(const short8*)(smem + LW1 + (ks * 5 + ct) * 512 + lane * 8);
            accA[ct] = __builtin_amdgcn_mfma_f32_16x16x32_bf16(wf, bA, accA[ct], 0, 0, 0);
            accB[ct] = __builtin_amdgcn_mfma_f32_16x16x32_bf16(wf, bB, accB[ct], 0, 0, 0);
          }
        }
#pragma unroll
        for (int ct = 0; ct < 5; ++ct) {          // relu + pack; masked per-row write
          uint2v uA, uB;
          uA[0] = pk2(fmaxf(accA[ct][0], 0.f), fmaxf(accA[ct][1], 0.f));
          uA[1] = pk2(fmaxf(accA[ct][2], 0.f), fmaxf(accA[ct][3], 0.f));
          uB[0] = pk2(fmaxf(accB[ct][0], 0.f), fmaxf(accB[ct][1], 0.f));
          uB[1] = pk2(fmaxf(accB[ct][2], 0.f), fmaxf(accB[ct][3], 0.f));
          if (midxA == g)
            *(uint2v*)(hbuf + l16 * SH + ct * 16 + quad * 4) = uA;
          if (midxB == g)
            *(uint2v*)(hbuf + (16 + l16) * SH + ct * 16 + quad * 4) = uB;
        }
      }

      // ---- L2/L3/L4 per tile (sequential: keeps acc live-set at 20 VGPRs;
      //      W fragments stream from global, L1-hot on the 2nd tile) ----
#pragma unroll
      for (int t = 0; t < 2; ++t) {
        unsigned short* hrow = hbuf + (t * 16 + l16) * SH;
        const int midx = (t == 0) ? midxA : midxB;

#pragma unroll
        for (int L = 0; L < 2; ++L) {             // L2, L3 (bias via k=80, pad col 1.0)
          short8 hf[3];
#pragma unroll
          for (int ks = 0; ks < 3; ++ks)
            hf[ks] = *(const short8*)(hrow + ks * 32 + quad * 8);
          floatx4 acc[5];
#pragma unroll
          for (int ct = 0; ct < 5; ++ct) acc[ct] = (floatx4){0.f, 0.f, 0.f, 0.f};
          const unsigned short* wbase = wsw + ((L == 0) ? W2SW : W3SW);
#pragma unroll
          for (int ks = 0; ks < 3; ++ks)
#pragma unroll
            for (int ct = 0; ct < 5; ++ct) {
              short8 wf = *(const short8*)(wbase + (ks * 5 + ct) * 512 + lane * 8);
              acc[ct] = __builtin_amdgcn_mfma_f32_16x16x32_bf16(wf, hf[ks], acc[ct], 0, 0, 0);
            }
#pragma unroll
          for (int ct = 0; ct < 5; ++ct) {
            uint2v u;
            u[0] = pk2(fmaxf(acc[ct][0], 0.f), fmaxf(acc[ct][1], 0.f));
            u[1] = pk2(fmaxf(acc[ct][2], 0.f), fmaxf(acc[ct][3], 0.f));
            *(uint2v*)(hrow + ct * 16 + quad * 4) = u;
          }
        }
        // ---- L4: W4 frags from global (L2-hot); packed float2 out stores ----
        {
          short8 hf[3];
#pragma unroll
          for (int ks = 0; ks < 3; ++ks)
            hf[ks] = *(const short8*)(hrow + ks * 32 + quad * 8);
          floatx4 acc[2];
#pragma unroll
          for (int ct = 0; ct < 2; ++ct) acc[ct] = (floatx4){0.f, 0.f, 0.f, 0.f};
#pragma unroll
          for (int ks = 0; ks < 3; ++ks)
#pragma unroll
            for (int ct = 0; ct < 2; ++ct) {
              short8 wf = *(const short8*)(wsw + W4SW + (g * 6 + ks * 2 + ct) * 512 + lane * 8);
              acc[ct] = __builtin_amdgcn_mfma_f32_16x16x32_bf16(wf, hf[ks], acc[ct], 0, 0, 0);
            }
          if (midx == g) {
            float* op = out + (trow + t * 16 + l16) * ADIM;  // n = ct*16+quad*4+r, n<18
            *(floatx2*)(op + quad * 4)     = (floatx2){acc[0][0], acc[0][1]};
            *(floatx2*)(op + quad * 4 + 2) = (floatx2){acc[0][2], acc[0][3]};
            if (quad == 0)
              *(floatx2*)(op + 16) = (floatx2){acc[1][0], acc[1][1]};
          }
        }
      }
    }
  }
}

extern "C" void kernel_launch(void* const* d_in, const int* in_sizes, int n_in,
                              void* d_out, int out_size, void* d_ws, size_t ws_size,
                              hipStream_t stream) {
  const float* state = (const float*)d_in[0];
  const int*   idx   = (const int*)d_in[1];
  const float* W1    = (const float*)d_in[2];
  const float* b1    = (const float*)d_in[3];
  const float* W2    = (const float*)d_in[4];
  const float* b2    = (const float*)d_in[5];
  const float* W3    = (const float*)d_in[6];
  const float* b3    = (const float*)d_in[7];
  const float* W4    = (const float*)d_in[8];
  const float* b4    = (const float*)d_in[9];
  float*       out   = (float*)d_out;
  unsigned short* wsw = (unsigned short*)d_ws;   // 284672 B used

  convert_weights<<<(WTOT + 255) / 256, 256, 0, stream>>>(W1, b1, W2, W3, W4, b2, b3, b4, wsw);
  gym_fused<<<GRID, THREADS, 0, stream>>>(state, idx, wsw, out);
}

// Round 2
// 327.157 us; speedup vs baseline: 1.0931x; 1.0931x over previous
//
#include <hip/hip_runtime.h>

// GymNetwork: routed MLP, B=262144, D=128 -> F=80 -> 80 -> 80 -> A=18, G=8 (idx sorted).
// f32 I/O, bf16 MFMA compute (threshold 6e-2 = 8*bf16_eps*max|ref|).
//
// R12 (fixing R11's scratch-spill: WRITE_SIZE 310MB, VGPR demoted to 64, 253us):
// Keep R11's wins (32 rows/wave sharing every weight read across 2 tiles; bias-in-k for
// all 4 layers; W2/W3/W4 streamed from global L1/L2; W1-only in LDS) but restructure
// every layer ct-OUTER so only the in-flight ct-pair's accumulators are live:
//   L1: 3 blocks (ct{0,1},{2,3},{4}), acc live 16 (was 40); bias ks=4 explicit, no ternary.
//   L2/L3/L4: BOTH tiles together (global weight reads halved to 36KB/slab), ct-pair outer.
// Peak live ~95 VGPR < 128 cap -> no scratch, 2 blocks/CU x 8 waves co-resident.

#define B_TOT   262144
#define DDIM    128
#define FDIM    80
#define ADIM    18
#define SH      104    // LDS stride (shorts) for h rows; 208B breaks pow2 bank stride
#define THREADS 512
#define SLAB    256    // rows per block-iteration (8 waves x 32)
#define NSLAB   2      // block rows = 512
#define GRID    (B_TOT / (SLAB * NSLAB))   // 512 blocks = 2/CU

// swizzled bf16 weight workspace in d_ws (shorts); 512-short (1KB) chunks, lane-major
#define W1SW    0                       // 200 chunks: (g*25 + ks*5 + ct); ks=4 = b1 col
#define W2SW    102400                  // 15 chunks: (ks*5+ct); k=80 holds b2, 81..95 zero
#define W3SW    110080                  // 15 chunks; k=80 holds b3
#define W4SW    117760                  // 48 chunks: (g*6+ks*2+ct); k=80 holds b4
#define NCHUNK  278
#define WTOT    (NCHUNK * 512)          // 142336 shorts = 284672 bytes

// LDS layout (shorts)
#define LW1     0                       // 25 chunks (current g) = 12800
#define LHB     12800                   // 8 waves x 32 x SH = 26624
#define LDS_SH  39424                   // 78848 B -> 2 blocks/CU

typedef __attribute__((ext_vector_type(8))) short short8;
typedef __attribute__((ext_vector_type(2))) unsigned int uint2v;
typedef __attribute__((ext_vector_type(4))) float floatx4;
typedef __attribute__((ext_vector_type(2))) float floatx2;

static __device__ __forceinline__ unsigned short f2bf(float f) {
  union { float f; unsigned u; } v; v.f = f;
  unsigned r = v.u + 0x7fffu + ((v.u >> 16) & 1u);   // RNE
  return (unsigned short)(r >> 16);
}
// pack two f32 -> bf16x2 (lo | hi<<16), RNE
static __device__ __forceinline__ unsigned pk2(float a, float b) {
  union { float f; unsigned u; } x, y; x.f = a; y.f = b;
  unsigned ra = x.u + 0x7fffu + ((x.u >> 16) & 1u);
  unsigned rb = y.u + 0x7fffu + ((y.u >> 16) & 1u);
  return (ra >> 16) | (rb & 0xffff0000u);
}

// ---- prologue: f32 weights -> bf16 swizzled chunks; biases folded into extra-k cols ----
// chunk: ws[chunk*512 + lane*8 + j] = W[n = ct*16 + (lane&15)][k = ks*32 + (lane>>4)*8 + j]
__global__ void convert_weights(const float* __restrict__ W1, const float* __restrict__ b1,
                                const float* __restrict__ W2, const float* __restrict__ W3,
                                const float* __restrict__ W4, const float* __restrict__ b2,
                                const float* __restrict__ b3, const float* __restrict__ b4,
                                unsigned short* __restrict__ ws) {
  int t = blockIdx.x * 256 + threadIdx.x;
  if (t >= WTOT) return;
  int chunk = t >> 9, r = t & 511;
  int lane = r >> 3, j = r & 7;
  int l16 = lane & 15, quad = lane >> 4;
  float val;
  if (chunk < 200) {                              // W1: [G][80][128] + ks=4 bias col
    int g = chunk / 25, rem = chunk % 25, ks = rem / 5, ct = rem % 5;
    int n = ct * 16 + l16, k = ks * 32 + quad * 8 + j;
    val = (ks < 4) ? W1[(g * FDIM + n) * DDIM + k]
                   : ((quad == 0 && j == 0) ? b1[g * FDIM + n] : 0.f);
  } else if (chunk < 215) {                       // W2: 80x80 -> 80x96, k80 = b2[n]
    int c = chunk - 200, ks = c / 5, ct = c % 5;
    int n = ct * 16 + l16, k = ks * 32 + quad * 8 + j;
    val = (k < FDIM) ? W2[n * FDIM + k] : (k == FDIM ? b2[n] : 0.f);
  } else if (chunk < 230) {                       // W3, k80 = b3[n]
    int c = chunk - 215, ks = c / 5, ct = c % 5;
    int n = ct * 16 + l16, k = ks * 32 + quad * 8 + j;
    val = (k < FDIM) ? W3[n * FDIM + k] : (k == FDIM ? b3[n] : 0.f);
  } else {                                        // W4: Gx18x80 -> Gx32x96, k80 = b4[g][n]
    int c = chunk - 230, g = c / 6, rem = c % 6, ks = rem >> 1, ct = rem & 1;
    int n = ct * 16 + l16, k = ks * 32 + quad * 8 + j;
    val = (n < ADIM) ? ((k < FDIM) ? W4[(g * ADIM + n) * FDIM + k]
                                   : (k == FDIM ? b4[g * ADIM + n] : 0.f)) : 0.f;
  }
  ws[t] = f2bf(val);
}

// W1[g] (25 chunks incl. bias col) -> LDS; barrier pair; block-uniform call sites
static __device__ __forceinline__ void stage_game(
    int g, const unsigned short* __restrict__ wsw, unsigned short* smem, int tid)
{
  __syncthreads();                                // all waves done with old W1
  const short8* src = (const short8*)(wsw + W1SW + g * (25 * 512));
  short8* dst = (short8*)(smem + LW1);
#pragma unroll
  for (int i = 0; i < 4; ++i) {
    int t = i * THREADS + tid;
    if (t < 1600) dst[t] = src[t];
  }
  __syncthreads();                                // new W1 visible
}

#define Z4 ((floatx4){0.f, 0.f, 0.f, 0.f})
#define MFMA(a, b, c) __builtin_amdgcn_mfma_f32_16x16x32_bf16((a), (b), (c), 0, 0, 0)

// relu + pack + h-store of one ct's 4-float acc (row ROW of this wave's hbuf)
#define H_STORE(ROW, CT, ACC) {                                            \
    uint2v u_;                                                             \
    u_[0] = pk2(fmaxf((ACC)[0], 0.f), fmaxf((ACC)[1], 0.f));               \
    u_[1] = pk2(fmaxf((ACC)[2], 0.f), fmaxf((ACC)[3], 0.f));               \
    *(uint2v*)(hbuf + (ROW) * SH + (CT) * 16 + quad * 4) = u_;             \
  }

// L1 ct-pair: each W1 LDS read feeds tile A and tile B; ks=4 chunk = b1 x bfrag(1.0)
#define L1_TWO(CT0, CT1) {                                                 \
    floatx4 aA0 = Z4, aB0 = Z4, aA1 = Z4, aB1 = Z4;                        \
    _Pragma("unroll")                                                      \
    for (int ks = 0; ks < 4; ++ks) {                                       \
      short8 wf0 = *(const short8*)(smem + LW1 + (ks * 5 + CT0) * 512 + lane * 8); \
      short8 wf1 = *(const short8*)(smem + LW1 + (ks * 5 + CT1) * 512 + lane * 8); \
      aA0 = MFMA(wf0, afrag[0][ks], aA0);                                  \
      aB0 = MFMA(wf0, afrag[1][ks], aB0);                                  \
      aA1 = MFMA(wf1, afrag[0][ks], aA1);                                  \
      aB1 = MFMA(wf1, afrag[1][ks], aB1);                                  \
    }                                                                      \
    {                                                                      \
      short8 wf0 = *(const short8*)(smem + LW1 + (20 + CT0) * 512 + lane * 8); \
      short8 wf1 = *(const short8*)(smem + LW1 + (20 + CT1) * 512 + lane * 8); \
      aA0 = MFMA(wf0, bfrag, aA0);  aB0 = MFMA(wf0, bfrag, aB0);           \
      aA1 = MFMA(wf1, bfrag, aA1);  aB1 = MFMA(wf1, bfrag, aB1);           \
    }                                                                      \
    if (midxA == g) { H_STORE(l16, CT0, aA0); H_STORE(l16, CT1, aA1); }    \
    if (midxB == g) { H_STORE(16 + l16, CT0, aB0); H_STORE(16 + l16, CT1, aB1); } \
  }

#define L1_ONE(CT) {                                                       \
    floatx4 aA = Z4, aB = Z4;                                              \
    _Pragma("unroll")                                                      \
    for (int ks = 0; ks < 4; ++ks) {                                       \
      short8 wf = *(const short8*)(smem + LW1 + (ks * 5 + CT) * 512 + lane * 8); \
      aA = MFMA(wf, afrag[0][ks], aA);                                     \
      aB = MFMA(wf, afrag[1][ks], aB);                                     \
    }                                                                      \
    {                                                                      \
      short8 wf = *(const short8*)(smem + LW1 + (20 + CT) * 512 + lane * 8); \
      aA = MFMA(wf, bfrag, aA);  aB = MFMA(wf, bfrag, aB);                 \
    }                                                                      \
    if (midxA == g) H_STORE(l16, CT, aA);                                  \
    if (midxB == g) H_STORE(16 + l16, CT, aB);                             \
  }

// L2/L3 ct-pair: weights from global (WB), h-frags from regs; unconditional h writes
#define L23_TWO(WB, CT0, CT1) {                                            \
    floatx4 aA0 = Z4, aB0 = Z4, aA1 = Z4, aB1 = Z4;                        \
    _Pragma("unroll")                                                      \
    for (int ks = 0; ks < 3; ++ks) {                                       \
      short8 wf0 = *(const short8*)((WB) + (ks * 5 + CT0) * 512 + lane * 8); \
      short8 wf1 = *(const short8*)((WB) + (ks * 5 + CT1) * 512 + lane * 8); \
      aA0 = MFMA(wf0, hfA[ks], aA0);                                       \
      aB0 = MFMA(wf0, hfB[ks], aB0);                                       \
      aA1 = MFMA(wf1, hfA[ks], aA1);                                       \
      aB1 = MFMA(wf1, hfB[ks], aB1);                                       \
    }                                                                      \
    H_STORE(l16, CT0, aA0);      H_STORE(l16, CT1, aA1);                   \
    H_STORE(16 + l16, CT0, aB0); H_STORE(16 + l16, CT1, aB1);              \
  }

#define L23_ONE(WB, CT) {                                                  \
    floatx4 aA = Z4, aB = Z4;                                              \
    _Pragma("unroll")                                                      \
    for (int ks = 0; ks < 3; ++ks) {                                       \
      short8 wf = *(const short8*)((WB) + (ks * 5 + CT) * 512 + lane * 8); \
      aA = MFMA(wf, hfA[ks], aA);                                          \
      aB = MFMA(wf, hfB[ks], aB);                                          \
    }                                                                      \
    H_STORE(l16, CT, aA);                                                  \
    H_STORE(16 + l16, CT, aB);                                             \
  }

__global__ __launch_bounds__(THREADS, 4) void gym_fused(
    const float* __restrict__ state, const int* __restrict__ idx,
    const unsigned short* __restrict__ wsw, float* __restrict__ out)
{
  __shared__ __align__(16) unsigned short smem[LDS_SH];

  const int tid  = threadIdx.x;
  const int lane = tid & 63;
  const int wv   = tid >> 6;
  const int l16  = lane & 15;
  const int quad = lane >> 4;
  unsigned short* hbuf = smem + LHB + wv * (32 * SH);
  const size_t blk0 = (size_t)blockIdx.x * (SLAB * NSLAB);

  // ---- hbuf pad cols 80..95 for all 32 rows: col80 = 1.0 (bias-in-k), 81..95 = 0 ----
  {
    int row = lane >> 1, grp = lane & 1;          // 32 rows x 2 groups of 8 shorts
    short8 v = (short8){0, 0, 0, 0, 0, 0, 0, 0};
    if (grp == 0) v[0] = (short)0x3F80;           // bf16 1.0 at col 80
    *(short8*)(hbuf + row * SH + 80 + grp * 8) = v;
  }

  // ---- constant B-frag for L1's ks=4 bias chunk: 1.0 at k=128 (quad 0, j 0) ----
  short8 bfrag = (short8){0, 0, 0, 0, 0, 0, 0, 0};
  if (quad == 0) bfrag[0] = (short)0x3F80;

  // ---- initial game (covered by stage_game's barrier pair) ----
  int curr_g = idx[blk0];
  stage_game(curr_g, wsw, smem, tid);

  for (int it = 0; it < NSLAB; ++it) {
    const size_t slab0 = blk0 + (size_t)it * SLAB;
    const size_t trow  = slab0 + wv * 32;         // this wave's 32 rows (2 x 16 tiles)
    const int tg_lo = idx[slab0];
    const int tg_hi = idx[slab0 + SLAB - 1];      // idx sorted
    const int midxA = idx[trow + l16];            // tile-A lane row's game
    const int midxB = idx[trow + 16 + l16];       // tile-B lane row's game

    // ---- state B'-fragments for both tiles: row = l16, k = quad*8+j ----
    short8 afrag[2][4];
#pragma unroll
    for (int t = 0; t < 2; ++t) {
      const float* sp = state + (trow + t * 16 + l16) * DDIM + quad * 8;
#pragma unroll
      for (int ks = 0; ks < 4; ++ks) {
        floatx4 va = *(const floatx4*)(sp + ks * 32);
        floatx4 vb = *(const floatx4*)(sp + ks * 32 + 4);
        short8 f;
        unsigned u0 = pk2(va[0], va[1]), u1 = pk2(va[2], va[3]);
        unsigned u2 = pk2(vb[0], vb[1]), u3 = pk2(vb[2], vb[3]);
        f[0] = (short)(u0 & 0xffff); f[1] = (short)(u0 >> 16);
        f[2] = (short)(u1 & 0xffff); f[3] = (short)(u1 >> 16);
        f[4] = (short)(u2 & 0xffff); f[5] = (short)(u2 >> 16);
        f[6] = (short)(u3 & 0xffff); f[7] = (short)(u3 >> 16);
        afrag[t][ks] = f;
      }
    }

    for (int g = tg_lo; g <= tg_hi; ++g) {        // block-uniform loop (slab range)
      if (g != curr_g) { stage_game(g, wsw, smem, tid); curr_g = g; }

      // ---- L1: ct-pair outer; each W1 read -> 2 MFMAs; 16 acc regs live ----
      L1_TWO(0, 1)
      L1_TWO(2, 3)
      L1_ONE(4)

      // ---- L2: both tiles, weights streamed from global (L1/L2-resident) ----
      {
        short8 hfA[3], hfB[3];
#pragma unroll
        for (int ks = 0; ks < 3; ++ks) {
          hfA[ks] = *(const short8*)(hbuf + l16 * SH + ks * 32 + quad * 8);
          hfB[ks] = *(const short8*)(hbuf + (16 + l16) * SH + ks * 32 + quad * 8);
        }
        const unsigned short* wb = wsw + W2SW;
        L23_TWO(wb, 0, 1)
        L23_TWO(wb, 2, 3)
        L23_ONE(wb, 4)
      }
      // ---- L3 ----
      {
        short8 hfA[3], hfB[3];
#pragma unroll
        for (int ks = 0; ks < 3; ++ks) {
          hfA[ks] = *(const short8*)(hbuf + l16 * SH + ks * 32 + quad * 8);
          hfB[ks] = *(const short8*)(hbuf + (16 + l16) * SH + ks * 32 + quad * 8);
        }
        const unsigned short* wb = wsw + W3SW;
        L23_TWO(wb, 0, 1)
        L23_TWO(wb, 2, 3)
        L23_ONE(wb, 4)
      }
      // ---- L4: both tiles share W4 chunk reads; packed float2 out stores ----
      {
        short8 hfA[3], hfB[3];
#pragma unroll
        for (int ks = 0; ks < 3; ++ks) {
          hfA[ks] = *(const short8*)(hbuf + l16 * SH + ks * 32 + quad * 8);
          hfB[ks] = *(const short8*)(hbuf + (16 + l16) * SH + ks * 32 + quad * 8);
        }
        floatx4 aA0 = Z4, aB0 = Z4, aA1 = Z4, aB1 = Z4;
#pragma unroll
        for (int ks = 0; ks < 3; ++ks) {
          short8 wf0 = *(const short8*)(wsw + W4SW + (g * 6 + ks * 2 + 0) * 512 + lane * 8);
          short8 wf1 = *(const short8*)(wsw + W4SW + (g * 6 + ks * 2 + 1) * 512 + lane * 8);
          aA0 = MFMA(wf0, hfA[ks], aA0);
          aB0 = MFMA(wf0, hfB[ks], aB0);
          aA1 = MFMA(wf1, hfA[ks], aA1);
          aB1 = MFMA(wf1, hfB[ks], aB1);
        }
        if (midxA == g) {                          // n = ct*16 + quad*4 + r, valid n<18
          float* op = out + (trow + l16) * ADIM;
          *(floatx2*)(op + quad * 4)     = (floatx2){aA0[0], aA0[1]};
          *(floatx2*)(op + quad * 4 + 2) = (floatx2){aA0[2], aA0[3]};
          if (quad == 0)
            *(floatx2*)(op + 16) = (floatx2){aA1[0], aA1[1]};
        }
        if (midxB == g) {
          float* op = out + (trow + 16 + l16) * ADIM;
          *(floatx2*)(op + quad * 4)     = (floatx2){aB0[0], aB0[1]};
          *(floatx2*)(op + quad * 4 + 2) = (floatx2){aB0[2], aB0[3]};
          if (quad == 0)
            *(floatx2*)(op + 16) = (floatx2){aB1[0], aB1[1]};
        }
      }
    }
  }
}

extern "C" void kernel_launch(void* const* d_in, const int* in_sizes, int n_in,
                              void* d_out, int out_size, void* d_ws, size_t ws_size,
                              hipStream_t stream) {
  const float* state = (const float*)d_in[0];
  const int*   idx   = (const int*)d_in[1];
  const float* W1    = (const float*)d_in[2];
  const float* b1    = (const float*)d_in[3];
  const float* W2    = (const float*)d_in[4];
  const float* b2    = (const float*)d_in[5];
  const float* W3    = (const float*)d_in[6];
  const float* b3    = (const float*)d_in[7];
  const float* W4    = (const float*)d_in[8];
  const float* b4    = (const float*)d_in[9];
  float*       out   = (float*)d_out;
  unsigned short* wsw = (unsigned short*)d_ws;   // 284672 B used

  convert_weights<<<(WTOT + 255) / 256, 256, 0, stream>>>(W1, b1, W2, W3, W4, b2, b3, b4, wsw);
  gym_fused<<<GRID, THREADS, 0, stream>>>(state, idx, wsw, out);
}